// Round 3
// baseline (6222.100 us; speedup 1.0000x reference)
//
#include <hip/hip_runtime.h>

// ---------------------------------------------------------------------------
// Bidirectional GRU (B=128, T=512, E=H=256) + linear head.
// Phase 1: G[v][c] = (emb[v] @ W_ih_d.T + b_ih (+ b_hh for r,z)) * gate_scale
//          bf16, columns PERMUTED per recurrence wave layout (scales baked:
//          r,z * -log2(e); n * 2*log2(e)).
// Phase 2: 16 WGs (2 dirs x 8 batch-groups of 16), 512 threads.
//          W_hh in regs (MFMA A-frags). 48 mfma_16x16x32_bf16 per step.
//          NO per-step __syncthreads: per-k-chunk produced-step counters in
//          LDS (wave w produces exactly chunk w). Waves pipeline across step
//          boundaries; no vmcnt drain -> gather latency fully hidden.
// ---------------------------------------------------------------------------

typedef float f32x4 __attribute__((ext_vector_type(4)));
typedef short s16x8 __attribute__((ext_vector_type(8)));

#define VOCAB   30000
#define GCOLS   1536
#define HB_STR  280     // bf16 elems per h row; 560 B stride
#define HBUF    (16 * HB_STR)
#define HS_STR  260     // f32 elements per h row for epilogue
#define SRF     (-1.4426950408889634f)   // -log2(e), sigmoid gates
#define SNF     (2.8853900817779268f)    // 2*log2(e), tanh gate

#if defined(__has_builtin)
#if __has_builtin(__builtin_amdgcn_cvt_pk_bf16_f32)
#define HAVE_PK 1
#endif
#endif

static __device__ __forceinline__ unsigned short f2bf(float f) {
    unsigned u = __builtin_bit_cast(unsigned, f);
    u += 0x7fffu + ((u >> 16) & 1u);            // RNE
    return (unsigned short)(u >> 16);
}
#ifdef HAVE_PK
typedef __bf16 bf16x2_t __attribute__((ext_vector_type(2)));
static __device__ __forceinline__ unsigned pk2(float a, float b) {
    bf16x2_t v = __builtin_amdgcn_cvt_pk_bf16_f32(a, b);
    return __builtin_bit_cast(unsigned, v);
}
#else
static __device__ __forceinline__ unsigned pk2(float a, float b) {
    return (unsigned)f2bf(a) | ((unsigned)f2bf(b) << 16);
}
#endif
static __device__ __forceinline__ float bf_lo(unsigned v) {
    return __builtin_bit_cast(float, v << 16);
}
static __device__ __forceinline__ float bf_hi(unsigned v) {
    return __builtin_bit_cast(float, v & 0xffff0000u);
}
static __device__ __forceinline__ s16x8 pack_bf8(float4 a, float4 b, float s) {
    union { s16x8 v; unsigned u[4]; } r;
    r.u[0] = pk2(a.x * s, a.y * s); r.u[1] = pk2(a.z * s, a.w * s);
    r.u[2] = pk2(b.x * s, b.y * s); r.u[3] = pk2(b.z * s, b.w * s);
    return r.v;
}
static __device__ __forceinline__ f32x4 mfma16(s16x8 a, s16x8 b, f32x4 c) {
    return __builtin_amdgcn_mfma_f32_16x16x32_bf16(a, b, c, 0, 0, 0);
}
static __device__ __forceinline__ float sig2(float x) {      // 1/(1+2^x)
    return __builtin_amdgcn_rcpf(1.0f + __builtin_amdgcn_exp2f(x));
}

// permuted col c = d*768 + tl*16 + u, tl = 6*w + t,
// orig gate row = (t>>1)*256 + 32*w + ((t&1)<<4) + u
// t in {0,1}=r, {2,3}=z, {4,5}=n  (lo/hi 16-blocks)

// ---------------------------------------------------------------------------
// Phase 1: gate table.  grid (6 N-strips of 256 cols, 60 M-blocks of 512 rows)
// ---------------------------------------------------------------------------
__global__ __launch_bounds__(512, 2)
void gru_table_kernel(const float* __restrict__ emb,
                      const float* __restrict__ Wih_f, const float* __restrict__ bih_f,
                      const float* __restrict__ bhh_f,
                      const float* __restrict__ Wih_b, const float* __restrict__ bih_b,
                      const float* __restrict__ bhh_b,
                      unsigned short* __restrict__ G) {
    __shared__ unsigned short aS[16 * HB_STR];
    const int tid  = threadIdx.x;
    const int lane = tid & 63;
    const int w    = tid >> 6;       // wave 0..7
    const int u    = lane & 15;
    const int q    = lane >> 4;
    const int strip = blockIdx.x;    // 0..5
    const int by    = blockIdx.y;    // 0..59

    // B-fragments (weights, pre-scaled) for this wave's 2 N-tiles.
    s16x8 breg[2][8];
    float beta[2];
    int   ntg_j[2];
#pragma unroll
    for (int j = 0; j < 2; ++j) {
        int ntg = strip * 16 + w * 2 + j;        // global N-tile 0..95
        ntg_j[j] = ntg;
        int dd = (ntg >= 48) ? 1 : 0;
        int tl = ntg - dd * 48;
        int wp = tl / 6;
        int t  = tl - wp * 6;
        int orig = (t >> 1) * 256 + 32 * wp + ((t & 1) << 4) + u;
        const float* Wih = dd ? Wih_b : Wih_f;
        const float* bih = dd ? bih_b : bih_f;
        const float* bhh = dd ? bhh_b : bhh_f;
        const float scl = (t < 4) ? SRF : SNF;
        beta[j] = (bih[orig] + ((t < 4) ? bhh[orig] : 0.0f)) * scl;
#pragma unroll
        for (int kt = 0; kt < 8; ++kt) {
            const float* p = Wih + orig * 256 + kt * 32 + q * 8;
            float4 x0 = *(const float4*)p;
            float4 x1 = *(const float4*)(p + 4);
            breg[j][kt] = pack_bf8(x0, x1, scl);
        }
    }

    for (int mt = 0; mt < 32; ++mt) {
        const int v0 = by * 512 + mt * 16;
        // stage 16 emb rows -> bf16 LDS (A-layout source)
        {
            int row = tid >> 5;
            int c8  = (tid & 31) * 8;
            int v   = v0 + row;
            float4 e0 = make_float4(0.f, 0.f, 0.f, 0.f), e1 = e0;
            if (v < VOCAB) {
                const float* p = emb + (size_t)v * 256 + c8;
                e0 = *(const float4*)p;
                e1 = *(const float4*)(p + 4);
            }
            unsigned* dp = (unsigned*)&aS[row * HB_STR + c8];
            dp[0] = pk2(e0.x, e0.y); dp[1] = pk2(e0.z, e0.w);
            dp[2] = pk2(e1.x, e1.y); dp[3] = pk2(e1.z, e1.w);
        }
        __syncthreads();

        f32x4 acc0 = {0.f, 0.f, 0.f, 0.f}, acc1 = acc0;
#pragma unroll
        for (int kt = 0; kt < 8; ++kt) {
            s16x8 af = *(const s16x8*)&aS[u * HB_STR + kt * 32 + q * 8];
            acc0 = mfma16(af, breg[0][kt], acc0);
            acc1 = mfma16(af, breg[1][kt], acc1);
        }
#pragma unroll
        for (int j = 0; j < 2; ++j) {
            f32x4 a = j ? acc1 : acc0;
#pragma unroll
            for (int r = 0; r < 4; ++r) {
                int v = v0 + q * 4 + r;
                if (v < VOCAB)
                    G[(size_t)v * GCOLS + ntg_j[j] * 16 + u] = f2bf(a[r] + beta[j]);
            }
        }
        __syncthreads();
    }
}

// ---------------------------------------------------------------------------
// Phase 2: recurrence. grid = 16 (dir = bx>>3, batch group = bx&3? no: &7).
// Per-chunk flag sync instead of per-step barrier.
// ---------------------------------------------------------------------------
__global__ __launch_bounds__(512, 2)
void gru_rnn_kernel(const int* __restrict__ inp,
                    const float* __restrict__ Whh_f, const float* __restrict__ bhh_f,
                    const float* __restrict__ Whh_b, const float* __restrict__ bhh_b,
                    const float* __restrict__ W_lin, const float* __restrict__ b_lin,
                    const unsigned short* __restrict__ G,
                    float* __restrict__ out) {
    __shared__ int            toks[16][513];       // +1 pad
    __shared__ unsigned short hB[2 * HBUF];        // double-buffered h (bf16)
    __shared__ unsigned       hflag[8];            // chunk j produced-step ctr
    __shared__ float          hs[16 * HS_STR];     // final h fp32 for epilogue

    const int tid  = threadIdx.x;
    const int lane = tid & 63;
    const int w    = tid >> 6;          // wave 0..7  (produces hidden chunk w)
    const int b    = lane & 15;         // batch within group
    const int q    = lane >> 4;
    const int d    = blockIdx.x >> 3;   // 0 fwd, 1 bwd
    const int b0   = (blockIdx.x & 7) * 16;

    const float* Whh = d ? Whh_b : Whh_f;
    const float* bhh = d ? bhh_b : bhh_f;

    // W_hh as A-fragments (pre-scaled), register/AGPR resident.
    s16x8 wreg[6][8];
#pragma unroll
    for (int t = 0; t < 6; ++t) {
        int orig = (t >> 1) * 256 + 32 * w + ((t & 1) << 4) + b;
        const float scl = (t < 4) ? SRF : SNF;
#pragma unroll
        for (int kt = 0; kt < 8; ++kt) {
            const float* p = Whh + orig * 256 + kt * 32 + q * 8;
            float4 x0 = *(const float4*)p;
            float4 x1 = *(const float4*)(p + 4);
            wreg[t][kt] = pack_bf8(x0, x1, scl);
        }
    }

    for (int i = tid; i < 16 * 512; i += 512) {
        int bb = i >> 9, t = i & 511;
        toks[bb][t] = inp[(b0 + bb) * 512 + t];
    }
    for (int i = tid; i < 2 * HBUF; i += 512) hB[i] = 0;   // h0 = 0
    if (tid < 8) hflag[tid] = 0;                            // step-0 h ready
    __syncthreads();

    const int i0    = 32 * w + 4 * q;              // this lane's hidden base
    const int hboff = b * HB_STR + q * 8;
    const size_t gcol = (size_t)d * 768 + 96 * w + 4 * q;

    // b_hh_n (pre-scaled) kept in regs for acc init
    f32x4 bhn_lo, bhn_hi;
#pragma unroll
    for (int r = 0; r < 4; ++r) {
        bhn_lo[r] = SNF * bhh[512 + i0 + r];
        bhn_hi[r] = SNF * bhh[512 + i0 + 16 + r];
    }

    float hreg[8];
#pragma unroll
    for (int i = 0; i < 8; ++i) hreg[i] = 0.f;

    // prologue: issue step-0 gather, stage step-1 token
    uint2 xr0, xr1, xz0, xz1, xn0, xn1;
    {
        int tok0 = toks[b][d ? 511 : 0];
        const uint2* gp = (const uint2*)(G + (size_t)tok0 * GCOLS + gcol);
        xr0 = gp[0];  xr1 = gp[4];
        xz0 = gp[8];  xz1 = gp[12];
        xn0 = gp[16]; xn1 = gp[20];
    }
    int tok_nxt = toks[b][d ? 510 : 1];

#pragma unroll 2
    for (int ts = 0; ts < 512; ++ts) {
        const int rb = (ts & 1) * HBUF;
        // unpack current x at step top (co-issues under other waves' MFMA),
        // then immediately re-issue next step's gather (no vmcnt drain exists
        // anywhere in the loop now -> latency fully hidden).
        float xrf[8] = {bf_lo(xr0.x), bf_hi(xr0.x), bf_lo(xr0.y), bf_hi(xr0.y),
                        bf_lo(xr1.x), bf_hi(xr1.x), bf_lo(xr1.y), bf_hi(xr1.y)};
        float xzf[8] = {bf_lo(xz0.x), bf_hi(xz0.x), bf_lo(xz0.y), bf_hi(xz0.y),
                        bf_lo(xz1.x), bf_hi(xz1.x), bf_lo(xz1.y), bf_hi(xz1.y)};
        float xnf[8] = {bf_lo(xn0.x), bf_hi(xn0.x), bf_lo(xn0.y), bf_hi(xn0.y),
                        bf_lo(xn1.x), bf_hi(xn1.x), bf_lo(xn1.y), bf_hi(xn1.y)};
        {
            const uint2* gp = (const uint2*)(G + (size_t)tok_nxt * GCOLS + gcol);
            xr0 = gp[0];  xr1 = gp[4];
            xz0 = gp[8];  xz1 = gp[12];
            xn0 = gp[16]; xn1 = gp[20];
            int s2 = ts + 2; if (s2 > 511) s2 = 511;
            tok_nxt = toks[b][d ? 511 - s2 : s2];
        }

        f32x4 acc0 = {0.f, 0.f, 0.f, 0.f}, acc1 = acc0, acc2 = acc0, acc3 = acc0;
        f32x4 acc4 = bhn_lo, acc5 = bhn_hi;
        // k-chunk loop, rotated to start at self-produced chunk; per-chunk
        // acquire on the producer's step counter (usually already satisfied).
#pragma unroll
        for (int j = 0; j < 8; ++j) {
            const int kt = (w + j) & 7;
            if (j != 0) {
                while (__hip_atomic_load(&hflag[kt], __ATOMIC_ACQUIRE,
                                         __HIP_MEMORY_SCOPE_WORKGROUP) < (unsigned)ts)
                    __builtin_amdgcn_s_sleep(1);
            }
            s16x8 hf = *(const s16x8*)&hB[rb + hboff + kt * 32];
            acc0 = mfma16(wreg[0][kt], hf, acc0);
            acc1 = mfma16(wreg[1][kt], hf, acc1);
            acc2 = mfma16(wreg[2][kt], hf, acc2);
            acc3 = mfma16(wreg[3][kt], hf, acc3);
            acc4 = mfma16(wreg[4][kt], hf, acc4);
            acc5 = mfma16(wreg[5][kt], hf, acc5);
        }
        // in-lane GRU pointwise (scales pre-baked)
#pragma unroll
        for (int g = 0; g < 2; ++g) {
            const f32x4 ar = g ? acc1 : acc0;
            const f32x4 az = g ? acc3 : acc2;
            const f32x4 an = g ? acc5 : acc4;
#pragma unroll
            for (int r = 0; r < 4; ++r) {
                const int i = g * 4 + r;
                float rg = sig2(xrf[i] + ar[r]);
                float zg = sig2(xzf[i] + az[r]);
                float tg = sig2(fmaf(rg, an[r], xnf[i]));
                float ng = fmaf(-2.0f, tg, 1.0f);
                hreg[i] = fmaf(zg, hreg[i] - ng, ng);
            }
        }
        // write h_new chunk w to the other buffer, then release the flag
        {
            unsigned p0 = pk2(hreg[0], hreg[1]);
            unsigned p1 = pk2(hreg[2], hreg[3]);
            unsigned p2 = pk2(hreg[4], hreg[5]);
            unsigned p3 = pk2(hreg[6], hreg[7]);
            unsigned short* wb = &hB[((ts + 1) & 1) * HBUF + b * HB_STR + i0];
            *(uint2*)wb        = make_uint2(p0, p1);
            *(uint2*)(wb + 16) = make_uint2(p2, p3);
        }
        if (lane == 0)
            __hip_atomic_store(&hflag[w], (unsigned)(ts + 1), __ATOMIC_RELEASE,
                               __HIP_MEMORY_SCOPE_WORKGROUP);
    }

    __syncthreads();
    // epilogue: out[b][c] += h_d[b] . W_lin[c, d*256:+256]  (+ b_lin once)
    {
        f32x4 lo = {hreg[0], hreg[1], hreg[2], hreg[3]};
        f32x4 hi = {hreg[4], hreg[5], hreg[6], hreg[7]};
        *(f32x4*)&hs[b * HS_STR + i0]      = lo;
        *(f32x4*)&hs[b * HS_STR + i0 + 16] = hi;
    }
    __syncthreads();
    if (tid < 160) {
        int bb = tid / 10;
        int c  = tid - bb * 10;
        float acc = d ? 0.0f : b_lin[c];
        const float* wl = W_lin + c * 512 + d * 256;
        const float* hp = &hs[bb * HS_STR];
        for (int i = 0; i < 256; ++i) acc += hp[i] * wl[i];
        atomicAdd(&out[(b0 + bb) * 10 + c], acc);
    }
}

// ---------------------------------------------------------------------------
extern "C" void kernel_launch(void* const* d_in, const int* in_sizes, int n_in,
                              void* d_out, int out_size, void* d_ws, size_t ws_size,
                              hipStream_t stream) {
    const int*   inp   = (const int*)d_in[0];
    const float* emb   = (const float*)d_in[1];
    const float* Wih_f = (const float*)d_in[2];
    const float* Whh_f = (const float*)d_in[3];
    const float* bih_f = (const float*)d_in[4];
    const float* bhh_f = (const float*)d_in[5];
    const float* Wih_b = (const float*)d_in[6];
    const float* Whh_b = (const float*)d_in[7];
    const float* bih_b = (const float*)d_in[8];
    const float* bhh_b = (const float*)d_in[9];
    const float* W_lin = (const float*)d_in[10];
    const float* b_lin = (const float*)d_in[11];
    float* out = (float*)d_out;
    unsigned short* G = (unsigned short*)d_ws;   // 30000*1536*2 B = 92.16 MB

    hipMemsetAsync(d_out, 0, (size_t)out_size * sizeof(float), stream);
    hipLaunchKernelGGL(gru_table_kernel, dim3(6, 60), dim3(512), 0, stream,
                       emb, Wih_f, bih_f, bhh_f, Wih_b, bih_b, bhh_b, G);
    hipLaunchKernelGGL(gru_rnn_kernel, dim3(16), dim3(512), 0, stream,
                       inp, Whh_f, bhh_f, Whh_b, bhh_b, W_lin, b_lin, G, out);
}

// Round 4
// 1748.457 us; speedup vs baseline: 3.5586x; 3.5586x over previous
//
#include <hip/hip_runtime.h>

// ---------------------------------------------------------------------------
// Bidirectional GRU (B=128, T=512, E=H=256) + linear head.
// Phase 1: G[v][c] = (emb[v] @ W_ih_d.T + b_ih (+ b_hh for r,z)) * gate_scale
//          bf16, columns PERMUTED per recurrence wave layout (scales baked:
//          r,z * -log2(e); n * 2*log2(e)).
// Phase 2: 16 WGs (2 dirs x 8 batch-groups of 16), 512 threads.
//          W_hh in regs (MFMA A-frags). 48 mfma_16x16x32_bf16 per step.
//          h double-buffered in LDS; ONE raw barrier per step:
//          s_waitcnt lgkmcnt(0) + s_barrier (NO vmcnt drain!) so the G-table
//          gather prefetch genuinely stays in flight across the barrier.
//          r/z gate xg folded into MFMA C-init.
// ---------------------------------------------------------------------------

typedef float f32x4 __attribute__((ext_vector_type(4)));
typedef short s16x8 __attribute__((ext_vector_type(8)));

#define VOCAB   30000
#define GCOLS   1536
#define HB_STR  280     // bf16 elems per h row; 560 B stride (2-way max = free)
#define HBUF    (16 * HB_STR)
#define HS_STR  260     // f32 elements per h row for epilogue
#define SRF     (-1.4426950408889634f)   // -log2(e), sigmoid gates
#define SNF     (2.8853900817779268f)    // 2*log2(e), tanh gate

// workgroup barrier WITHOUT vmcnt drain (LDS ordering only)
#define BARRIER_LDS() asm volatile("s_waitcnt lgkmcnt(0)\n\ts_barrier" ::: "memory")

#if defined(__has_builtin)
#if __has_builtin(__builtin_amdgcn_cvt_pk_bf16_f32)
#define HAVE_PK 1
#endif
#endif

static __device__ __forceinline__ unsigned short f2bf(float f) {
    unsigned u = __builtin_bit_cast(unsigned, f);
    u += 0x7fffu + ((u >> 16) & 1u);            // RNE
    return (unsigned short)(u >> 16);
}
#ifdef HAVE_PK
typedef __bf16 bf16x2_t __attribute__((ext_vector_type(2)));
static __device__ __forceinline__ unsigned pk2(float a, float b) {
    bf16x2_t v = __builtin_amdgcn_cvt_pk_bf16_f32(a, b);
    return __builtin_bit_cast(unsigned, v);
}
#else
static __device__ __forceinline__ unsigned pk2(float a, float b) {
    return (unsigned)f2bf(a) | ((unsigned)f2bf(b) << 16);
}
#endif
static __device__ __forceinline__ float bf_lo(unsigned v) {
    return __builtin_bit_cast(float, v << 16);
}
static __device__ __forceinline__ float bf_hi(unsigned v) {
    return __builtin_bit_cast(float, v & 0xffff0000u);
}
static __device__ __forceinline__ s16x8 pack_bf8(float4 a, float4 b, float s) {
    union { s16x8 v; unsigned u[4]; } r;
    r.u[0] = pk2(a.x * s, a.y * s); r.u[1] = pk2(a.z * s, a.w * s);
    r.u[2] = pk2(b.x * s, b.y * s); r.u[3] = pk2(b.z * s, b.w * s);
    return r.v;
}
static __device__ __forceinline__ f32x4 mfma16(s16x8 a, s16x8 b, f32x4 c) {
    return __builtin_amdgcn_mfma_f32_16x16x32_bf16(a, b, c, 0, 0, 0);
}
static __device__ __forceinline__ float sig2(float x) {      // 1/(1+2^x)
    return __builtin_amdgcn_rcpf(1.0f + __builtin_amdgcn_exp2f(x));
}

// permuted col c = d*768 + tl*16 + u, tl = 6*w + t,
// orig gate row = (t>>1)*256 + 32*w + ((t&1)<<4) + u
// t in {0,1}=r, {2,3}=z, {4,5}=n  (lo/hi 16-blocks)

// ---------------------------------------------------------------------------
// Phase 1: gate table.  grid (6 N-strips of 256 cols, 60 M-blocks of 512 rows)
// ---------------------------------------------------------------------------
__global__ __launch_bounds__(512, 2)
void gru_table_kernel(const float* __restrict__ emb,
                      const float* __restrict__ Wih_f, const float* __restrict__ bih_f,
                      const float* __restrict__ bhh_f,
                      const float* __restrict__ Wih_b, const float* __restrict__ bih_b,
                      const float* __restrict__ bhh_b,
                      unsigned short* __restrict__ G) {
    __shared__ unsigned short aS[16 * HB_STR];
    const int tid  = threadIdx.x;
    const int lane = tid & 63;
    const int w    = tid >> 6;       // wave 0..7
    const int u    = lane & 15;
    const int q    = lane >> 4;
    const int strip = blockIdx.x;    // 0..5
    const int by    = blockIdx.y;    // 0..59

    // B-fragments (weights, pre-scaled) for this wave's 2 N-tiles.
    s16x8 breg[2][8];
    float beta[2];
    int   ntg_j[2];
#pragma unroll
    for (int j = 0; j < 2; ++j) {
        int ntg = strip * 16 + w * 2 + j;        // global N-tile 0..95
        ntg_j[j] = ntg;
        int dd = (ntg >= 48) ? 1 : 0;
        int tl = ntg - dd * 48;
        int wp = tl / 6;
        int t  = tl - wp * 6;
        int orig = (t >> 1) * 256 + 32 * wp + ((t & 1) << 4) + u;
        const float* Wih = dd ? Wih_b : Wih_f;
        const float* bih = dd ? bih_b : bih_f;
        const float* bhh = dd ? bhh_b : bhh_f;
        const float scl = (t < 4) ? SRF : SNF;
        beta[j] = (bih[orig] + ((t < 4) ? bhh[orig] : 0.0f)) * scl;
#pragma unroll
        for (int kt = 0; kt < 8; ++kt) {
            const float* p = Wih + orig * 256 + kt * 32 + q * 8;
            float4 x0 = *(const float4*)p;
            float4 x1 = *(const float4*)(p + 4);
            breg[j][kt] = pack_bf8(x0, x1, scl);
        }
    }

    for (int mt = 0; mt < 32; ++mt) {
        const int v0 = by * 512 + mt * 16;
        // stage 16 emb rows -> bf16 LDS (A-layout source)
        {
            int row = tid >> 5;
            int c8  = (tid & 31) * 8;
            int v   = v0 + row;
            float4 e0 = make_float4(0.f, 0.f, 0.f, 0.f), e1 = e0;
            if (v < VOCAB) {
                const float* p = emb + (size_t)v * 256 + c8;
                e0 = *(const float4*)p;
                e1 = *(const float4*)(p + 4);
            }
            unsigned* dp = (unsigned*)&aS[row * HB_STR + c8];
            dp[0] = pk2(e0.x, e0.y); dp[1] = pk2(e0.z, e0.w);
            dp[2] = pk2(e1.x, e1.y); dp[3] = pk2(e1.z, e1.w);
        }
        __syncthreads();

        f32x4 acc0 = {0.f, 0.f, 0.f, 0.f}, acc1 = acc0;
#pragma unroll
        for (int kt = 0; kt < 8; ++kt) {
            s16x8 af = *(const s16x8*)&aS[u * HB_STR + kt * 32 + q * 8];
            acc0 = mfma16(af, breg[0][kt], acc0);
            acc1 = mfma16(af, breg[1][kt], acc1);
        }
#pragma unroll
        for (int j = 0; j < 2; ++j) {
            f32x4 a = j ? acc1 : acc0;
#pragma unroll
            for (int r = 0; r < 4; ++r) {
                int v = v0 + q * 4 + r;
                if (v < VOCAB)
                    G[(size_t)v * GCOLS + ntg_j[j] * 16 + u] = f2bf(a[r] + beta[j]);
            }
        }
        __syncthreads();
    }
}

// ---------------------------------------------------------------------------
// Phase 2: recurrence. grid = 16 (dir = bx>>3, batch group = bx&7), 512 thr.
// ---------------------------------------------------------------------------
__global__ __launch_bounds__(512, 2)
void gru_rnn_kernel(const int* __restrict__ inp,
                    const float* __restrict__ Whh_f, const float* __restrict__ bhh_f,
                    const float* __restrict__ Whh_b, const float* __restrict__ bhh_b,
                    const float* __restrict__ W_lin, const float* __restrict__ b_lin,
                    const unsigned short* __restrict__ G,
                    float* __restrict__ out) {
    __shared__ int            toks[16][513];       // +1 pad
    __shared__ unsigned short hB[2 * HBUF];        // double-buffered h (bf16)
    __shared__ float          hs[16 * HS_STR];     // final h fp32 for epilogue

    const int tid  = threadIdx.x;
    const int lane = tid & 63;
    const int w    = tid >> 6;          // wave 0..7
    const int b    = lane & 15;         // batch within group
    const int q    = lane >> 4;
    const int d    = blockIdx.x >> 3;   // 0 fwd, 1 bwd
    const int b0   = (blockIdx.x & 7) * 16;

    const float* Whh = d ? Whh_b : Whh_f;
    const float* bhh = d ? bhh_b : bhh_f;

    // W_hh as A-fragments (pre-scaled), register resident.
    s16x8 wreg[6][8];
#pragma unroll
    for (int t = 0; t < 6; ++t) {
        int orig = (t >> 1) * 256 + 32 * w + ((t & 1) << 4) + b;
        const float scl = (t < 4) ? SRF : SNF;
#pragma unroll
        for (int kt = 0; kt < 8; ++kt) {
            const float* p = Whh + orig * 256 + kt * 32 + q * 8;
            float4 x0 = *(const float4*)p;
            float4 x1 = *(const float4*)(p + 4);
            wreg[t][kt] = pack_bf8(x0, x1, scl);
        }
    }

    for (int i = tid; i < 16 * 512; i += 512) {
        int bb = i >> 9, t = i & 511;
        toks[bb][t] = inp[(b0 + bb) * 512 + t];
    }
    for (int i = tid; i < 2 * HBUF; i += 512) hB[i] = 0;   // h0 = 0
    __syncthreads();

    const int i0    = 32 * w + 4 * q;              // this lane's hidden base
    const int hboff = b * HB_STR + q * 8;
    const size_t gcol = (size_t)d * 768 + 96 * w + 4 * q;

    // b_hh_n (pre-scaled) in regs for n-acc init
    f32x4 bhn_lo, bhn_hi;
#pragma unroll
    for (int r = 0; r < 4; ++r) {
        bhn_lo[r] = SNF * bhh[512 + i0 + r];
        bhn_hi[r] = SNF * bhh[512 + i0 + 16 + r];
    }

    float hreg[8];
#pragma unroll
    for (int i = 0; i < 8; ++i) hreg[i] = 0.f;

    // prologue: issue step-0 gather, stage step-1 token
    uint2 xr0, xr1, xz0, xz1, xn0, xn1;
    {
        int tok0 = toks[b][d ? 511 : 0];
        const uint2* gp = (const uint2*)(G + (size_t)tok0 * GCOLS + gcol);
        xr0 = gp[0];  xr1 = gp[4];
        xz0 = gp[8];  xz1 = gp[12];
        xn0 = gp[16]; xn1 = gp[20];
    }
    int tok_nxt = toks[b][d ? 510 : 1];

#pragma unroll 2
    for (int ts = 0; ts < 512; ++ts) {
        const int rb = (ts & 1) * HBUF;
        // r/z xg folded straight into MFMA C-init (vmcnt wait lands HERE,
        // covered by the whole previous step since the barrier no longer
        // drains vmcnt).  n xg kept separate (b_hh_n must sit inside r*(...)).
        f32x4 acc0 = {bf_lo(xr0.x), bf_hi(xr0.x), bf_lo(xr0.y), bf_hi(xr0.y)};
        f32x4 acc1 = {bf_lo(xr1.x), bf_hi(xr1.x), bf_lo(xr1.y), bf_hi(xr1.y)};
        f32x4 acc2 = {bf_lo(xz0.x), bf_hi(xz0.x), bf_lo(xz0.y), bf_hi(xz0.y)};
        f32x4 acc3 = {bf_lo(xz1.x), bf_hi(xz1.x), bf_lo(xz1.y), bf_hi(xz1.y)};
        float xnf[8] = {bf_lo(xn0.x), bf_hi(xn0.x), bf_lo(xn0.y), bf_hi(xn0.y),
                        bf_lo(xn1.x), bf_hi(xn1.x), bf_lo(xn1.y), bf_hi(xn1.y)};
        f32x4 acc4 = bhn_lo, acc5 = bhn_hi;
        // re-issue next step's gather immediately (stays in flight across the
        // LDS-only barrier below)
        {
            const uint2* gp = (const uint2*)(G + (size_t)tok_nxt * GCOLS + gcol);
            xr0 = gp[0];  xr1 = gp[4];
            xz0 = gp[8];  xz1 = gp[12];
            xn0 = gp[16]; xn1 = gp[20];
            int s2 = ts + 2; if (s2 > 511) s2 = 511;
            tok_nxt = toks[b][d ? 511 - s2 : s2];
        }
#pragma unroll
        for (int kt = 0; kt < 8; ++kt) {
            s16x8 hf = *(const s16x8*)&hB[rb + hboff + kt * 32];
            acc0 = mfma16(wreg[0][kt], hf, acc0);
            acc1 = mfma16(wreg[1][kt], hf, acc1);
            acc2 = mfma16(wreg[2][kt], hf, acc2);
            acc3 = mfma16(wreg[3][kt], hf, acc3);
            acc4 = mfma16(wreg[4][kt], hf, acc4);
            acc5 = mfma16(wreg[5][kt], hf, acc5);
        }
        // in-lane GRU pointwise (scales pre-baked; xr/xz already in accs)
#pragma unroll
        for (int g = 0; g < 2; ++g) {
            const f32x4 ar = g ? acc1 : acc0;
            const f32x4 az = g ? acc3 : acc2;
            const f32x4 an = g ? acc5 : acc4;
#pragma unroll
            for (int r = 0; r < 4; ++r) {
                const int i = g * 4 + r;
                float rg = sig2(ar[r]);
                float zg = sig2(az[r]);
                float tg = sig2(fmaf(rg, an[r], xnf[i]));
                float ng = fmaf(-2.0f, tg, 1.0f);
                hreg[i] = fmaf(zg, hreg[i] - ng, ng);
            }
        }
        // write h_new to the other buffer; ONE LDS-only barrier per step
        {
            unsigned p0 = pk2(hreg[0], hreg[1]);
            unsigned p1 = pk2(hreg[2], hreg[3]);
            unsigned p2 = pk2(hreg[4], hreg[5]);
            unsigned p3 = pk2(hreg[6], hreg[7]);
            unsigned short* wb = &hB[((ts + 1) & 1) * HBUF + b * HB_STR + i0];
            *(uint2*)wb        = make_uint2(p0, p1);
            *(uint2*)(wb + 16) = make_uint2(p2, p3);
        }
        BARRIER_LDS();
    }

    // epilogue: out[b][c] += h_d[b] . W_lin[c, d*256:+256]  (+ b_lin once)
    {
        f32x4 lo = {hreg[0], hreg[1], hreg[2], hreg[3]};
        f32x4 hi = {hreg[4], hreg[5], hreg[6], hreg[7]};
        *(f32x4*)&hs[b * HS_STR + i0]      = lo;
        *(f32x4*)&hs[b * HS_STR + i0 + 16] = hi;
    }
    __syncthreads();
    if (tid < 160) {
        int bb = tid / 10;
        int c  = tid - bb * 10;
        float acc = d ? 0.0f : b_lin[c];
        const float* wl = W_lin + c * 512 + d * 256;
        const float* hp = &hs[bb * HS_STR];
        for (int i = 0; i < 256; ++i) acc += hp[i] * wl[i];
        atomicAdd(&out[(b0 + bb) * 10 + c], acc);
    }
}

// ---------------------------------------------------------------------------
extern "C" void kernel_launch(void* const* d_in, const int* in_sizes, int n_in,
                              void* d_out, int out_size, void* d_ws, size_t ws_size,
                              hipStream_t stream) {
    const int*   inp   = (const int*)d_in[0];
    const float* emb   = (const float*)d_in[1];
    const float* Wih_f = (const float*)d_in[2];
    const float* Whh_f = (const float*)d_in[3];
    const float* bih_f = (const float*)d_in[4];
    const float* bhh_f = (const float*)d_in[5];
    const float* Wih_b = (const float*)d_in[6];
    const float* Whh_b = (const float*)d_in[7];
    const float* bih_b = (const float*)d_in[8];
    const float* bhh_b = (const float*)d_in[9];
    const float* W_lin = (const float*)d_in[10];
    const float* b_lin = (const float*)d_in[11];
    float* out = (float*)d_out;
    unsigned short* G = (unsigned short*)d_ws;   // 30000*1536*2 B = 92.16 MB

    hipMemsetAsync(d_out, 0, (size_t)out_size * sizeof(float), stream);
    hipLaunchKernelGGL(gru_table_kernel, dim3(6, 60), dim3(512), 0, stream,
                       emb, Wih_f, bih_f, bhh_f, Wih_b, bih_b, bhh_b, G);
    hipLaunchKernelGGL(gru_rnn_kernel, dim3(16), dim3(512), 0, stream,
                       inp, Whh_f, bhh_f, Whh_b, bhh_b, W_lin, b_lin, G, out);
}

// Round 5
// 1352.225 us; speedup vs baseline: 4.6014x; 1.2930x over previous
//
#include <hip/hip_runtime.h>

// ---------------------------------------------------------------------------
// Bidirectional GRU (B=128, T=512, E=H=256) + linear head.
// Phase 1 (unchanged layout): G[v][c] = (emb[v]@W_ih.T + b_ih (+b_hh r,z)) *
//          gate_scale, bf16, permuted: col = d*768 + (6*w8+t)*16 + u,
//          w8 in [0,8) over i-blocks of 32; t = {r,z,n}x{lo,hi}.
// Phase 2: 16 WGs x 256 threads (4 waves, 1 wave/SIMD, 512-reg budget).
//          Wave w owns i in [64w,64w+64) == w8 in {2w, 2w+1}: 12 M-tiles,
//          wreg = 96 A-frags = 384 regs -> NO SPILL (the R1-R4 bottleneck).
//          xg staged via global_load_lds into LDS (double-buffered, issued
//          one step ahead; zero VGPR cost). 96 mfma_16x16x32_bf16 / step.
// ---------------------------------------------------------------------------

typedef float f32x4 __attribute__((ext_vector_type(4)));
typedef short s16x8 __attribute__((ext_vector_type(8)));

#define VOCAB   30000
#define GCOLS   1536
#define HB_STR  280     // bf16 elems per h row (560 B; ≡48 mod 128)
#define HBUF    (16 * HB_STR)
#define GP_STR  1032    // bf16 elems per xgS row (2064 B; ≡16 mod 128)
#define HS_STR  260     // f32 elems per h row for epilogue
#define SRF     (-1.4426950408889634f)   // -log2(e), sigmoid gates
#define SNF     (2.8853900817779268f)    // 2*log2(e), tanh gate

#if defined(__has_builtin)
#if __has_builtin(__builtin_amdgcn_cvt_pk_bf16_f32)
#define HAVE_PK 1
#endif
#endif

static __device__ __forceinline__ unsigned short f2bf(float f) {
    unsigned u = __builtin_bit_cast(unsigned, f);
    u += 0x7fffu + ((u >> 16) & 1u);            // RNE
    return (unsigned short)(u >> 16);
}
#ifdef HAVE_PK
typedef __bf16 bf16x2_t __attribute__((ext_vector_type(2)));
static __device__ __forceinline__ unsigned pk2(float a, float b) {
    bf16x2_t v = __builtin_amdgcn_cvt_pk_bf16_f32(a, b);
    return __builtin_bit_cast(unsigned, v);
}
#else
static __device__ __forceinline__ unsigned pk2(float a, float b) {
    return (unsigned)f2bf(a) | ((unsigned)f2bf(b) << 16);
}
#endif
static __device__ __forceinline__ float bf_lo(unsigned v) {
    return __builtin_bit_cast(float, v << 16);
}
static __device__ __forceinline__ float bf_hi(unsigned v) {
    return __builtin_bit_cast(float, v & 0xffff0000u);
}
static __device__ __forceinline__ s16x8 pack_bf8(float4 a, float4 b, float s) {
    union { s16x8 v; unsigned u[4]; } r;
    r.u[0] = pk2(a.x * s, a.y * s); r.u[1] = pk2(a.z * s, a.w * s);
    r.u[2] = pk2(b.x * s, b.y * s); r.u[3] = pk2(b.z * s, b.w * s);
    return r.v;
}
static __device__ __forceinline__ f32x4 mfma16(s16x8 a, s16x8 b, f32x4 c) {
    return __builtin_amdgcn_mfma_f32_16x16x32_bf16(a, b, c, 0, 0, 0);
}
static __device__ __forceinline__ float sig2(float x) {      // 1/(1+2^x)
    return __builtin_amdgcn_rcpf(1.0f + __builtin_amdgcn_exp2f(x));
}
// async global->LDS, 16 B per lane, wave-uniform LDS base
static __device__ __forceinline__ void gload_lds16(const unsigned short* g, unsigned short* l) {
    __builtin_amdgcn_global_load_lds(
        (const __attribute__((address_space(1))) unsigned*)g,
        (__attribute__((address_space(3))) unsigned*)l, 16, 0, 0);
}

// ---------------------------------------------------------------------------
// Phase 1: gate table.  grid (6 N-strips of 256 cols, 60 M-blocks of 512 rows)
// ---------------------------------------------------------------------------
__global__ __launch_bounds__(512, 2)
void gru_table_kernel(const float* __restrict__ emb,
                      const float* __restrict__ Wih_f, const float* __restrict__ bih_f,
                      const float* __restrict__ bhh_f,
                      const float* __restrict__ Wih_b, const float* __restrict__ bih_b,
                      const float* __restrict__ bhh_b,
                      unsigned short* __restrict__ G) {
    __shared__ unsigned short aS[16 * HB_STR];
    const int tid  = threadIdx.x;
    const int lane = tid & 63;
    const int w    = tid >> 6;       // wave 0..7
    const int u    = lane & 15;
    const int q    = lane >> 4;
    const int strip = blockIdx.x;    // 0..5
    const int by    = blockIdx.y;    // 0..59

    s16x8 breg[2][8];
    float beta[2];
    int   ntg_j[2];
#pragma unroll
    for (int j = 0; j < 2; ++j) {
        int ntg = strip * 16 + w * 2 + j;        // global N-tile 0..95
        ntg_j[j] = ntg;
        int dd = (ntg >= 48) ? 1 : 0;
        int tl = ntg - dd * 48;
        int wp = tl / 6;
        int t  = tl - wp * 6;
        int orig = (t >> 1) * 256 + 32 * wp + ((t & 1) << 4) + u;
        const float* Wih = dd ? Wih_b : Wih_f;
        const float* bih = dd ? bih_b : bih_f;
        const float* bhh = dd ? bhh_b : bhh_f;
        const float scl = (t < 4) ? SRF : SNF;
        beta[j] = (bih[orig] + ((t < 4) ? bhh[orig] : 0.0f)) * scl;
#pragma unroll
        for (int kt = 0; kt < 8; ++kt) {
            const float* p = Wih + orig * 256 + kt * 32 + q * 8;
            float4 x0 = *(const float4*)p;
            float4 x1 = *(const float4*)(p + 4);
            breg[j][kt] = pack_bf8(x0, x1, scl);
        }
    }

    for (int mt = 0; mt < 32; ++mt) {
        const int v0 = by * 512 + mt * 16;
        {
            int row = tid >> 5;
            int c8  = (tid & 31) * 8;
            int v   = v0 + row;
            float4 e0 = make_float4(0.f, 0.f, 0.f, 0.f), e1 = e0;
            if (v < VOCAB) {
                const float* p = emb + (size_t)v * 256 + c8;
                e0 = *(const float4*)p;
                e1 = *(const float4*)(p + 4);
            }
            unsigned* dp = (unsigned*)&aS[row * HB_STR + c8];
            dp[0] = pk2(e0.x, e0.y); dp[1] = pk2(e0.z, e0.w);
            dp[2] = pk2(e1.x, e1.y); dp[3] = pk2(e1.z, e1.w);
        }
        __syncthreads();

        f32x4 acc0 = {0.f, 0.f, 0.f, 0.f}, acc1 = acc0;
#pragma unroll
        for (int kt = 0; kt < 8; ++kt) {
            s16x8 af = *(const s16x8*)&aS[u * HB_STR + kt * 32 + q * 8];
            acc0 = mfma16(af, breg[0][kt], acc0);
            acc1 = mfma16(af, breg[1][kt], acc1);
        }
#pragma unroll
        for (int j = 0; j < 2; ++j) {
            f32x4 a = j ? acc1 : acc0;
#pragma unroll
            for (int r = 0; r < 4; ++r) {
                int v = v0 + q * 4 + r;
                if (v < VOCAB)
                    G[(size_t)v * GCOLS + ntg_j[j] * 16 + u] = f2bf(a[r] + beta[j]);
            }
        }
        __syncthreads();
    }
}

// ---------------------------------------------------------------------------
// Phase 2: recurrence. grid = 16 (dir = bx>>3, batch group = bx&7), 256 thr.
// ---------------------------------------------------------------------------
__global__ __launch_bounds__(256, 1)
void gru_rnn_kernel(const int* __restrict__ inp,
                    const float* __restrict__ Whh_f, const float* __restrict__ bhh_f,
                    const float* __restrict__ Whh_b, const float* __restrict__ bhh_b,
                    const float* __restrict__ W_lin, const float* __restrict__ b_lin,
                    const unsigned short* __restrict__ G,
                    float* __restrict__ out) {
    __shared__ int            toks[16][513];          // 32.8 KB
    __shared__ unsigned short hB[2 * HBUF];           // 17.9 KB dbuf h (bf16)
    __shared__ unsigned short xgS[2][16][GP_STR];     // 66.0 KB dbuf xg (bf16)
    __shared__ float          bhnS[256];              // 1 KB
    __shared__ float          hs[16 * HS_STR];        // 16.6 KB epilogue

    const int tid  = threadIdx.x;
    const int lane = tid & 63;
    const int w    = tid >> 6;          // wave 0..3 (owns i in [64w,64w+64))
    const int b    = lane & 15;         // batch within group
    const int q    = lane >> 4;
    const int d    = blockIdx.x >> 3;   // 0 fwd, 1 bwd
    const int b0   = (blockIdx.x & 7) * 16;

    const float* Whh = d ? Whh_b : Whh_f;
    const float* bhh = d ? bhh_b : bhh_f;

    // W_hh as 96 A-fragments (pre-scaled): tile i = h*6+t, h in {0,1} picks
    // w8 = 2w+h (i-block of 32), t = {r,z,n}x{lo,hi}.  384 regs.
    s16x8 wreg[96];
#pragma unroll
    for (int h = 0; h < 2; ++h) {
#pragma unroll
        for (int t = 0; t < 6; ++t) {
            const int w8 = 2 * w + h;
            const int orig = (t >> 1) * 256 + 32 * w8 + ((t & 1) << 4) + b;
            const float scl = (t < 4) ? SRF : SNF;
#pragma unroll
            for (int kt = 0; kt < 8; ++kt) {
                const float* p = Whh + orig * 256 + kt * 32 + q * 8;
                wreg[(h * 6 + t) * 8 + kt] =
                    pack_bf8(*(const float4*)p, *(const float4*)(p + 4), scl);
            }
        }
    }

    for (int i = tid; i < 16 * 512; i += 256) {
        int bb = i >> 9, t = i & 511;
        toks[bb][t] = inp[(b0 + bb) * 512 + t];
    }
    for (int i = tid; i < 2 * HBUF; i += 256) hB[i] = 0;   // h0 = 0
    bhnS[tid] = SNF * bhh[512 + tid];
    __syncthreads();

    // prologue: stage step-0 xg into xgS[0] (wave w stages batches 4w..4w+3)
    {
        int t0 = d ? 511 : 0;
#pragma unroll
        for (int j = 0; j < 4; ++j) {
            int bb = 4 * w + j;
            int tok = toks[bb][t0];
            const unsigned short* gb = G + (size_t)tok * GCOLS + (d ? 512 : 0) + lane * 8;
            gload_lds16(gb,       &xgS[0][bb][0]);
            gload_lds16(gb + 512, &xgS[0][bb][512]);
        }
    }
    __syncthreads();   // drains vmcnt -> xgS[0] valid

    const int  xoff = d ? 256 : 0;      // dir-window shift inside stored row
    const int  hbq  = b * HB_STR + q * 8;
    float hreg[16];
#pragma unroll
    for (int i = 0; i < 16; ++i) hreg[i] = 0.f;

#pragma unroll 1
    for (int ts = 0; ts < 512; ++ts) {
        const int rb = (ts & 1) * HBUF;
        const int pn = (ts + 1) & 1;
        // 1) issue NEXT step's xg gather (async, zero VGPR cost, ~full-step cover)
        {
            int s1 = (ts < 511) ? ts + 1 : 511;
            int t1 = d ? 511 - s1 : s1;
#pragma unroll
            for (int j = 0; j < 4; ++j) {
                int bb = 4 * w + j;
                int tok = toks[bb][t1];
                const unsigned short* gb = G + (size_t)tok * GCOLS + (d ? 512 : 0) + lane * 8;
                gload_lds16(gb,       &xgS[pn][bb][0]);
                gload_lds16(gb + 512, &xgS[pn][bb][512]);
            }
        }
        // 2) hg^T = W_hh * h^T : 96 MFMAs, acc[i=h*6+t]
        f32x4 acc[12];
#pragma unroll
        for (int h = 0; h < 2; ++h) {
            acc[h * 6 + 0] = f32x4{0.f, 0.f, 0.f, 0.f};
            acc[h * 6 + 1] = f32x4{0.f, 0.f, 0.f, 0.f};
            acc[h * 6 + 2] = f32x4{0.f, 0.f, 0.f, 0.f};
            acc[h * 6 + 3] = f32x4{0.f, 0.f, 0.f, 0.f};
            acc[h * 6 + 4] = *(const f32x4*)&bhnS[64 * w + 32 * h + 4 * q];
            acc[h * 6 + 5] = *(const f32x4*)&bhnS[64 * w + 32 * h + 16 + 4 * q];
        }
#pragma unroll
        for (int kt = 0; kt < 8; ++kt) {
            s16x8 hf = *(const s16x8*)&hB[rb + hbq + kt * 32];
#pragma unroll
            for (int i = 0; i < 12; ++i)
                acc[i] = mfma16(wreg[i * 8 + kt], hf, acc[i]);
        }
        // 3) pointwise GRU, xg read from LDS (written during previous step)
        const unsigned short* xrow = &xgS[ts & 1][b][0];
#pragma unroll
        for (int h = 0; h < 2; ++h) {
            const int cb = 96 * (2 * w + h) + 4 * q + xoff;
#pragma unroll
            for (int l = 0; l < 2; ++l) {
                uint2 uxr = *(const uint2*)&xrow[cb + 16 * (0 + l)];
                uint2 uxz = *(const uint2*)&xrow[cb + 16 * (2 + l)];
                uint2 uxn = *(const uint2*)&xrow[cb + 16 * (4 + l)];
                const f32x4 ar = acc[h * 6 + 0 + l];
                const f32x4 az = acc[h * 6 + 2 + l];
                const f32x4 an = acc[h * 6 + 4 + l];
                float xr[4] = {bf_lo(uxr.x), bf_hi(uxr.x), bf_lo(uxr.y), bf_hi(uxr.y)};
                float xz[4] = {bf_lo(uxz.x), bf_hi(uxz.x), bf_lo(uxz.y), bf_hi(uxz.y)};
                float xn[4] = {bf_lo(uxn.x), bf_hi(uxn.x), bf_lo(uxn.y), bf_hi(uxn.y)};
#pragma unroll
                for (int r = 0; r < 4; ++r) {
                    float rg = sig2(xr[r] + ar[r]);
                    float zg = sig2(xz[r] + az[r]);
                    float tg = sig2(fmaf(rg, an[r], xn[r]));
                    float ng = fmaf(-2.0f, tg, 1.0f);
                    const int hi_ = h * 8 + l * 4 + r;
                    hreg[hi_] = fmaf(zg, hreg[hi_] - ng, ng);
                }
            }
        }
        // 4) write h_new (bf16) to the other h buffer
        {
            unsigned short* wb = &hB[pn * HBUF + b * HB_STR + 64 * w + 4 * q];
#pragma unroll
            for (int h = 0; h < 2; ++h)
#pragma unroll
                for (int l = 0; l < 2; ++l) {
                    unsigned p0 = pk2(hreg[h * 8 + l * 4 + 0], hreg[h * 8 + l * 4 + 1]);
                    unsigned p1 = pk2(hreg[h * 8 + l * 4 + 2], hreg[h * 8 + l * 4 + 3]);
                    *(uint2*)&wb[32 * h + 16 * l] = make_uint2(p0, p1);
                }
        }
        // 5) one barrier: drains lgkm (h writes) AND vmcnt (xg stage) together
        __syncthreads();
    }

    // epilogue: out[b][c] += h_d[b] . W_lin[c, d*256:+256]  (+ b_lin once)
#pragma unroll
    for (int h = 0; h < 2; ++h)
#pragma unroll
        for (int l = 0; l < 2; ++l) {
            f32x4 v = {hreg[h * 8 + l * 4 + 0], hreg[h * 8 + l * 4 + 1],
                       hreg[h * 8 + l * 4 + 2], hreg[h * 8 + l * 4 + 3]};
            *(f32x4*)&hs[b * HS_STR + 64 * w + 32 * h + 16 * l + 4 * q] = v;
        }
    __syncthreads();
    if (tid < 160) {
        int bb = tid / 10;
        int c  = tid - bb * 10;
        float acc = d ? 0.0f : b_lin[c];
        const float* wl = W_lin + c * 512 + d * 256;
        const float* hp = &hs[bb * HS_STR];
        for (int i = 0; i < 256; ++i) acc += hp[i] * wl[i];
        atomicAdd(&out[(b0 + bb) * 10 + c], acc);
    }
}

// ---------------------------------------------------------------------------
extern "C" void kernel_launch(void* const* d_in, const int* in_sizes, int n_in,
                              void* d_out, int out_size, void* d_ws, size_t ws_size,
                              hipStream_t stream) {
    const int*   inp   = (const int*)d_in[0];
    const float* emb   = (const float*)d_in[1];
    const float* Wih_f = (const float*)d_in[2];
    const float* Whh_f = (const float*)d_in[3];
    const float* bih_f = (const float*)d_in[4];
    const float* bhh_f = (const float*)d_in[5];
    const float* Wih_b = (const float*)d_in[6];
    const float* Whh_b = (const float*)d_in[7];
    const float* bih_b = (const float*)d_in[8];
    const float* bhh_b = (const float*)d_in[9];
    const float* W_lin = (const float*)d_in[10];
    const float* b_lin = (const float*)d_in[11];
    float* out = (float*)d_out;
    unsigned short* G = (unsigned short*)d_ws;   // 30000*1536*2 B = 92.16 MB

    hipMemsetAsync(d_out, 0, (size_t)out_size * sizeof(float), stream);
    hipLaunchKernelGGL(gru_table_kernel, dim3(6, 60), dim3(512), 0, stream,
                       emb, Wih_f, bih_f, bhh_f, Wih_b, bih_b, bhh_b, G);
    hipLaunchKernelGGL(gru_rnn_kernel, dim3(16), dim3(256), 0, stream,
                       inp, Whh_f, bhh_f, Whh_b, bhh_b, W_lin, b_lin, G, out);
}

// Round 6
// 1094.702 us; speedup vs baseline: 5.6838x; 1.2352x over previous
//
#include <hip/hip_runtime.h>

// ---------------------------------------------------------------------------
// Bidirectional GRU (B=128, T=512, E=H=256) + linear head.
// Phase 1 (unchanged): G[v][c] = (emb[v]@W_ih.T + b_ih (+b_hh r,z)) * scale,
//          bf16, permuted: col = d*768 + (6*w8+t)*16 + u  (t=2*gate+half).
// Phase 2: 16 WGs x 512 threads (8 waves, 2/SIMD -> latency hiding).
//          Wave w owns i in [32w,32w+32): 6 M-tiles, wreg = 48 frags = 192
//          regs -> fits the 256-reg budget WITH a second wave per SIMD
//          (R2 spilled because xg lived in VGPRs; R5 fixed spill but lost
//          overlap at 1 wave/SIMD). xg staged via global_load_lds (0 regs),
//          step processed in two column-halves so only 3 accs live at once.
// ---------------------------------------------------------------------------

typedef float f32x4 __attribute__((ext_vector_type(4)));
typedef short s16x8 __attribute__((ext_vector_type(8)));

#define VOCAB   30000
#define GCOLS   1536
#define HB_STR  280     // bf16 elems per h row (560 B)
#define HBUF    (16 * HB_STR)
#define GP_STR  1032    // bf16 elems per xgS row (2064 B)
#define HS_STR  260     // f32 elems per h row for epilogue
#define SRF     (-1.4426950408889634f)   // -log2(e), sigmoid gates
#define SNF     (2.8853900817779268f)    // 2*log2(e), tanh gate

#if defined(__has_builtin)
#if __has_builtin(__builtin_amdgcn_cvt_pk_bf16_f32)
#define HAVE_PK 1
#endif
#endif

static __device__ __forceinline__ unsigned short f2bf(float f) {
    unsigned u = __builtin_bit_cast(unsigned, f);
    u += 0x7fffu + ((u >> 16) & 1u);            // RNE
    return (unsigned short)(u >> 16);
}
#ifdef HAVE_PK
typedef __bf16 bf16x2_t __attribute__((ext_vector_type(2)));
static __device__ __forceinline__ unsigned pk2(float a, float b) {
    bf16x2_t v = __builtin_amdgcn_cvt_pk_bf16_f32(a, b);
    return __builtin_bit_cast(unsigned, v);
}
#else
static __device__ __forceinline__ unsigned pk2(float a, float b) {
    return (unsigned)f2bf(a) | ((unsigned)f2bf(b) << 16);
}
#endif
static __device__ __forceinline__ float bf_lo(unsigned v) {
    return __builtin_bit_cast(float, v << 16);
}
static __device__ __forceinline__ float bf_hi(unsigned v) {
    return __builtin_bit_cast(float, v & 0xffff0000u);
}
static __device__ __forceinline__ s16x8 pack_bf8(float4 a, float4 b, float s) {
    union { s16x8 v; unsigned u[4]; } r;
    r.u[0] = pk2(a.x * s, a.y * s); r.u[1] = pk2(a.z * s, a.w * s);
    r.u[2] = pk2(b.x * s, b.y * s); r.u[3] = pk2(b.z * s, b.w * s);
    return r.v;
}
static __device__ __forceinline__ f32x4 mfma16(s16x8 a, s16x8 b, f32x4 c) {
    return __builtin_amdgcn_mfma_f32_16x16x32_bf16(a, b, c, 0, 0, 0);
}
static __device__ __forceinline__ float sig2(float x) {      // 1/(1+2^x)
    return __builtin_amdgcn_rcpf(1.0f + __builtin_amdgcn_exp2f(x));
}
// async global->LDS, 16 B per lane, wave-uniform LDS base
static __device__ __forceinline__ void gload_lds16(const unsigned short* g, unsigned short* l) {
    __builtin_amdgcn_global_load_lds(
        (const __attribute__((address_space(1))) unsigned*)g,
        (__attribute__((address_space(3))) unsigned*)l, 16, 0, 0);
}

// ---------------------------------------------------------------------------
// Phase 1: gate table.  grid (6 N-strips of 256 cols, 60 M-blocks of 512 rows)
// ---------------------------------------------------------------------------
__global__ __launch_bounds__(512, 2)
void gru_table_kernel(const float* __restrict__ emb,
                      const float* __restrict__ Wih_f, const float* __restrict__ bih_f,
                      const float* __restrict__ bhh_f,
                      const float* __restrict__ Wih_b, const float* __restrict__ bih_b,
                      const float* __restrict__ bhh_b,
                      unsigned short* __restrict__ G) {
    __shared__ unsigned short aS[16 * HB_STR];
    const int tid  = threadIdx.x;
    const int lane = tid & 63;
    const int w    = tid >> 6;       // wave 0..7
    const int u    = lane & 15;
    const int q    = lane >> 4;
    const int strip = blockIdx.x;    // 0..5
    const int by    = blockIdx.y;    // 0..59

    s16x8 breg[2][8];
    float beta[2];
    int   ntg_j[2];
#pragma unroll
    for (int j = 0; j < 2; ++j) {
        int ntg = strip * 16 + w * 2 + j;        // global N-tile 0..95
        ntg_j[j] = ntg;
        int dd = (ntg >= 48) ? 1 : 0;
        int tl = ntg - dd * 48;
        int wp = tl / 6;
        int t  = tl - wp * 6;
        int orig = (t >> 1) * 256 + 32 * wp + ((t & 1) << 4) + u;
        const float* Wih = dd ? Wih_b : Wih_f;
        const float* bih = dd ? bih_b : bih_f;
        const float* bhh = dd ? bhh_b : bhh_f;
        const float scl = (t < 4) ? SRF : SNF;
        beta[j] = (bih[orig] + ((t < 4) ? bhh[orig] : 0.0f)) * scl;
#pragma unroll
        for (int kt = 0; kt < 8; ++kt) {
            const float* p = Wih + orig * 256 + kt * 32 + q * 8;
            float4 x0 = *(const float4*)p;
            float4 x1 = *(const float4*)(p + 4);
            breg[j][kt] = pack_bf8(x0, x1, scl);
        }
    }

    for (int mt = 0; mt < 32; ++mt) {
        const int v0 = by * 512 + mt * 16;
        {
            int row = tid >> 5;
            int c8  = (tid & 31) * 8;
            int v   = v0 + row;
            float4 e0 = make_float4(0.f, 0.f, 0.f, 0.f), e1 = e0;
            if (v < VOCAB) {
                const float* p = emb + (size_t)v * 256 + c8;
                e0 = *(const float4*)p;
                e1 = *(const float4*)(p + 4);
            }
            unsigned* dp = (unsigned*)&aS[row * HB_STR + c8];
            dp[0] = pk2(e0.x, e0.y); dp[1] = pk2(e0.z, e0.w);
            dp[2] = pk2(e1.x, e1.y); dp[3] = pk2(e1.z, e1.w);
        }
        __syncthreads();

        f32x4 acc0 = {0.f, 0.f, 0.f, 0.f}, acc1 = acc0;
#pragma unroll
        for (int kt = 0; kt < 8; ++kt) {
            s16x8 af = *(const s16x8*)&aS[u * HB_STR + kt * 32 + q * 8];
            acc0 = mfma16(af, breg[0][kt], acc0);
            acc1 = mfma16(af, breg[1][kt], acc1);
        }
#pragma unroll
        for (int j = 0; j < 2; ++j) {
            f32x4 a = j ? acc1 : acc0;
#pragma unroll
            for (int r = 0; r < 4; ++r) {
                int v = v0 + q * 4 + r;
                if (v < VOCAB)
                    G[(size_t)v * GCOLS + ntg_j[j] * 16 + u] = f2bf(a[r] + beta[j]);
            }
        }
        __syncthreads();
    }
}

// ---------------------------------------------------------------------------
// Phase 2: recurrence. grid = 16 (dir = bx>>3, batch group = bx&7), 512 thr.
// ---------------------------------------------------------------------------
__global__ __launch_bounds__(512, 2)
void gru_rnn_kernel(const int* __restrict__ inp,
                    const float* __restrict__ Whh_f, const float* __restrict__ bhh_f,
                    const float* __restrict__ Whh_b, const float* __restrict__ bhh_b,
                    const float* __restrict__ W_lin, const float* __restrict__ b_lin,
                    const unsigned short* __restrict__ G,
                    float* __restrict__ out) {
    __shared__ int            toks[16][513];          // 32.8 KB
    __shared__ unsigned short hB[2 * HBUF];           // 17.9 KB dbuf h (bf16)
    __shared__ unsigned short xgS[2][16][GP_STR];     // 66.0 KB dbuf xg (bf16)
    __shared__ float          bhnS[256];              // 1 KB
    __shared__ float          hs[16 * HS_STR];        // 16.6 KB epilogue

    const int tid  = threadIdx.x;
    const int lane = tid & 63;
    const int w    = tid >> 6;          // wave 0..7 (owns i in [32w,32w+32))
    const int b    = lane & 15;         // batch within group
    const int q    = lane >> 4;
    const int d    = blockIdx.x >> 3;   // 0 fwd, 1 bwd
    const int b0   = (blockIdx.x & 7) * 16;

    const float* Whh = d ? Whh_b : Whh_f;
    const float* bhh = d ? bhh_b : bhh_f;

    // W_hh as 48 A-fragments (pre-scaled): tile t = 2*gate + half.  192 regs.
    s16x8 wreg[48];
#pragma unroll
    for (int t = 0; t < 6; ++t) {
        const int orig = (t >> 1) * 256 + 32 * w + ((t & 1) << 4) + b;
        const float scl = (t < 4) ? SRF : SNF;
#pragma unroll
        for (int kt = 0; kt < 8; ++kt) {
            const float* p = Whh + orig * 256 + kt * 32 + q * 8;
            wreg[t * 8 + kt] =
                pack_bf8(*(const float4*)p, *(const float4*)(p + 4), scl);
        }
    }

    for (int i = tid; i < 16 * 512; i += 512) {
        int bb = i >> 9, t = i & 511;
        toks[bb][t] = inp[(b0 + bb) * 512 + t];
    }
    for (int i = tid; i < 2 * HBUF; i += 512) hB[i] = 0;   // h0 = 0
    if (tid < 256) bhnS[tid] = SNF * bhh[512 + tid];
    __syncthreads();

    // prologue: stage step-0 xg into xgS[0] (wave w stages batches 2w, 2w+1)
    {
        int t0 = d ? 511 : 0;
#pragma unroll
        for (int j = 0; j < 2; ++j) {
            int bb = 2 * w + j;
            int tok = toks[bb][t0];
            const unsigned short* gb = G + (size_t)tok * GCOLS + (d ? 512 : 0) + lane * 8;
            gload_lds16(gb,       &xgS[0][bb][0]);
            gload_lds16(gb + 512, &xgS[0][bb][512]);
        }
    }
    __syncthreads();   // drains vmcnt -> xgS[0] valid

    const int xoff = d ? 256 : 0;       // dir-window shift inside stored row
    const int hbq  = b * HB_STR + q * 8;
    float hreg[8];
#pragma unroll
    for (int i = 0; i < 8; ++i) hreg[i] = 0.f;

#pragma unroll 2
    for (int ts = 0; ts < 512; ++ts) {
        const int rb = (ts & 1) * HBUF;
        const int pn = (ts + 1) & 1;
        // 1) issue NEXT step's xg gather (async, zero VGPR cost)
        {
            int s1 = (ts < 511) ? ts + 1 : 511;
            int t1 = d ? 511 - s1 : s1;
#pragma unroll
            for (int j = 0; j < 2; ++j) {
                int bb = 2 * w + j;
                int tok = toks[bb][t1];
                const unsigned short* gb = G + (size_t)tok * GCOLS + (d ? 512 : 0) + lane * 8;
                gload_lds16(gb,       &xgS[pn][bb][0]);
                gload_lds16(gb + 512, &xgS[pn][bb][512]);
            }
        }
        // 2+3) two column-halves: 24 MFMAs + pointwise each; only 3 accs live
#pragma unroll
        for (int l = 0; l < 2; ++l) {
            f32x4 ar = {0.f, 0.f, 0.f, 0.f};
            f32x4 az = {0.f, 0.f, 0.f, 0.f};
            f32x4 an = *(const f32x4*)&bhnS[32 * w + 16 * l + 4 * q];
#pragma unroll
            for (int kt = 0; kt < 8; ++kt) {
                s16x8 hf = *(const s16x8*)&hB[rb + hbq + kt * 32];
                ar = mfma16(wreg[(0 + l) * 8 + kt], hf, ar);
                az = mfma16(wreg[(2 + l) * 8 + kt], hf, az);
                an = mfma16(wreg[(4 + l) * 8 + kt], hf, an);
            }
            const unsigned short* xrow = &xgS[ts & 1][b][xoff + 96 * w + 16 * l + 4 * q];
            uint2 uxr = *(const uint2*)&xrow[0];
            uint2 uxz = *(const uint2*)&xrow[32];
            uint2 uxn = *(const uint2*)&xrow[64];
            float xr[4] = {bf_lo(uxr.x), bf_hi(uxr.x), bf_lo(uxr.y), bf_hi(uxr.y)};
            float xz[4] = {bf_lo(uxz.x), bf_hi(uxz.x), bf_lo(uxz.y), bf_hi(uxz.y)};
            float xn[4] = {bf_lo(uxn.x), bf_hi(uxn.x), bf_lo(uxn.y), bf_hi(uxn.y)};
#pragma unroll
            for (int r = 0; r < 4; ++r) {
                float rg = sig2(xr[r] + ar[r]);
                float zg = sig2(xz[r] + az[r]);
                float tg = sig2(fmaf(rg, an[r], xn[r]));
                float ng = fmaf(-2.0f, tg, 1.0f);
                const int i = l * 4 + r;
                hreg[i] = fmaf(zg, hreg[i] - ng, ng);
            }
            // write this half's h_new (bf16) to the other h buffer
            unsigned p0 = pk2(hreg[l * 4 + 0], hreg[l * 4 + 1]);
            unsigned p1 = pk2(hreg[l * 4 + 2], hreg[l * 4 + 3]);
            *(uint2*)&hB[pn * HBUF + b * HB_STR + 32 * w + 16 * l + 4 * q] =
                make_uint2(p0, p1);
        }
        // 4) one barrier: drains lgkm (h writes) + vmcnt (xg stage) together
        __syncthreads();
    }

    // epilogue: out[b][c] += h_d[b] . W_lin[c, d*256:+256]  (+ b_lin once)
#pragma unroll
    for (int l = 0; l < 2; ++l) {
        f32x4 v = {hreg[l * 4 + 0], hreg[l * 4 + 1],
                   hreg[l * 4 + 2], hreg[l * 4 + 3]};
        *(f32x4*)&hs[b * HS_STR + 32 * w + 16 * l + 4 * q] = v;
    }
    __syncthreads();
    if (tid < 160) {
        int bb = tid / 10;
        int c  = tid - bb * 10;
        float acc = d ? 0.0f : b_lin[c];
        const float* wl = W_lin + c * 512 + d * 256;
        const float* hp = &hs[bb * HS_STR];
        for (int i = 0; i < 256; ++i) acc += hp[i] * wl[i];
        atomicAdd(&out[(b0 + bb) * 10 + c], acc);
    }
}

// ---------------------------------------------------------------------------
extern "C" void kernel_launch(void* const* d_in, const int* in_sizes, int n_in,
                              void* d_out, int out_size, void* d_ws, size_t ws_size,
                              hipStream_t stream) {
    const int*   inp   = (const int*)d_in[0];
    const float* emb   = (const float*)d_in[1];
    const float* Wih_f = (const float*)d_in[2];
    const float* Whh_f = (const float*)d_in[3];
    const float* bih_f = (const float*)d_in[4];
    const float* bhh_f = (const float*)d_in[5];
    const float* Wih_b = (const float*)d_in[6];
    const float* Whh_b = (const float*)d_in[7];
    const float* bih_b = (const float*)d_in[8];
    const float* bhh_b = (const float*)d_in[9];
    const float* W_lin = (const float*)d_in[10];
    const float* b_lin = (const float*)d_in[11];
    float* out = (float*)d_out;
    unsigned short* G = (unsigned short*)d_ws;   // 30000*1536*2 B = 92.16 MB

    hipMemsetAsync(d_out, 0, (size_t)out_size * sizeof(float), stream);
    hipLaunchKernelGGL(gru_table_kernel, dim3(6, 60), dim3(512), 0, stream,
                       emb, Wih_f, bih_f, bhh_f, Wih_b, bih_b, bhh_b, G);
    hipLaunchKernelGGL(gru_rnn_kernel, dim3(16), dim3(512), 0, stream,
                       inp, Whh_f, bhh_f, Whh_b, bhh_b, W_lin, b_lin, G, out);
}